// Round 12
// baseline (92.335 us; speedup 1.0000x reference)
//
#include <hip/hip_runtime.h>
#include <cstddef>

typedef __attribute__((ext_vector_type(8))) short bf16x8;
typedef __attribute__((ext_vector_type(4))) float f32x4;
typedef __attribute__((ext_vector_type(16))) float f32x16;
typedef unsigned short ushort_t;

namespace {
constexpr int Tt = 4, Hh = 44, Ww = 44, Cc = 384, NH = 12, HD = 32;
constexpr int NWIN = 25, NT = 400, NTP = 416, NPOS = Hh * Ww;
constexpr int NTOK = 2 * Tt * NPOS;                 // 15488 = 121*128
constexpr float SCALE = 0.17677669529663687f;       // 1/sqrt(32)
constexpr float LOG2E = 1.4426950408889634f;
constexpr size_t WN  = (size_t)3 * Cc * Cc;         // 442,368
constexpr size_t PWN = (size_t)Cc * Cc;             // 147,456
constexpr size_t PLN = (size_t)600 * NTP * HD;      // 7,987,200 per plane
}

__device__ __forceinline__ unsigned cvt_pk_bf16(float a, float b) {
  unsigned r;
  asm volatile("v_cvt_pk_bf16_f32 %0, %1, %2" : "=v"(r) : "v"(a), "v"(b));
  return r;  // lo16 = bf16(a), hi16 = bf16(b)
}

// async global->LDS, 16B per lane; LDS dest = wave-uniform base + lane*16
__device__ __forceinline__ void gload16(const void* g, void* l) {
  __builtin_amdgcn_global_load_lds(
      (const __attribute__((address_space(1))) unsigned int*)g,
      (__attribute__((address_space(3))) unsigned int*)l, 16, 0, 0);
}

// ---------------------------------------------------------------------------
// K0: fp32->bf16 conversion of qkv_w + proj_w, and zero-fill of invalid /
// pad rows in the K and V windowed planes (reference semantics: padded
// positions contribute zero K rows (exp(0)=1 in the denominator) and zero V
// rows). x is consumed fp32 directly by K1 now; Q plane needs no fill.
// ---------------------------------------------------------------------------
__global__ __launch_bounds__(256) void conv_wz(
    const float* __restrict__ w1, const float* __restrict__ w2,
    ushort_t* __restrict__ w1o, ushort_t* __restrict__ w2o,
    ushort_t* __restrict__ kpl, ushort_t* __restrict__ vpl) {
  constexpr int WN8 = (int)(WN / 8), PN8 = (int)(PWN / 8);
  constexpr int TOT8 = WN8 + PN8;
  constexpr int ZTOT = 50 * NTP * NH;  // 249,600 (bw,kk,head) triples
  const int i = blockIdx.x * 256 + threadIdx.x;
  if (i < TOT8) {
    const float* s;
    ushort_t* d;
    int j;
    if (i < WN8) { s = w1; d = w1o; j = i; }
    else         { s = w2; d = w2o; j = i - WN8; }
    const float4* s4 = (const float4*)s;
    float4 a = s4[2 * j], bq = s4[2 * j + 1];
    union { bf16x8 v; unsigned u[4]; } o;
    o.u[0] = cvt_pk_bf16(a.x, a.y);   o.u[1] = cvt_pk_bf16(a.z, a.w);
    o.u[2] = cvt_pk_bf16(bq.x, bq.y); o.u[3] = cvt_pk_bf16(bq.z, bq.w);
    ((bf16x8*)d)[j] = o.v;
  } else if (i < TOT8 + ZTOT) {
    const int j = i - TOT8;
    const int pair = j / NH, head = j - pair * NH;
    const int bw = pair / NTP, kk = pair - bw * NTP;
    const int win = bw % NWIN, hi5 = win / 5, wi5 = win % 5;
    bool fill;
    if (kk >= NT) {
      fill = true;
    } else {
      const int rem = kk % 100;
      const int hh = rem / 10, ww2 = rem - hh * 10;
      fill = (hi5 == 4 && hh >= 4) || (wi5 == 4 && ww2 >= 4);
    }
    if (fill) {
      const size_t off = ((size_t)(bw * NH + head) * NTP + kk) * HD;
      bf16x8 z;
      z[0]=0;z[1]=0;z[2]=0;z[3]=0;z[4]=0;z[5]=0;z[6]=0;z[7]=0;
#pragma unroll
      for (int p = 0; p < 4; ++p) {
        ((bf16x8*)(kpl + off))[p] = z;
        ((bf16x8*)(vpl + off))[p] = z;
      }
    }
  }
}

// ---------------------------------------------------------------------------
// K1: dense QKV GEMM [15488 x 384] @ [384 x 1152]^T, m97 structure (128x128
// tile, BK=32), reading x DIRECTLY as fp32: A staged per-thread via
// 2x float4 load -> 4x cvt_pk -> ds_write_b128 into the SAME swizzled layout
// the frag reads use (write-swizzle == read-swizzle). B (weights, bf16) via
// global_load_lds with pre-swizzled source. Linear grid 1089 with bijective
// XCD-chunk swizzle (q=136, r=1). Epilogue: direct uint2 scatter to window
// planes; Q pre-scaled by SCALE*LOG2E.
// ---------------------------------------------------------------------------
__global__ __launch_bounds__(256) void qkv_mfma(
    const float* __restrict__ xf, const ushort_t* __restrict__ wb,
    ushort_t* __restrict__ qpl, ushort_t* __restrict__ kpl,
    ushort_t* __restrict__ vpl) {
  __shared__ __align__(16) unsigned char As[8192];
  __shared__ __align__(16) unsigned char Bs[8192];
  // bijective XCD-chunk swizzle over 1089 work items (q=136, r=1)
  const unsigned bid = blockIdx.x;
  const unsigned xcd = bid & 7u, slot = bid >> 3;
  const unsigned wgid = (xcd == 0 ? 0u : 137u + (xcd - 1u) * 136u) + slot;
  const int nt = wgid % 9, mt = wgid / 9;
  const int tid = threadIdx.x, lane = tid & 63, wid = tid >> 6;
  const int wm = wid >> 1, wn = wid & 1;
  const int g = lane >> 4, q = lane & 15;
  const int m0 = mt * 128, n0 = nt * 128;

  const unsigned char* wB = (const unsigned char*)wb;

  const float* xp[2];
  unsigned xlds[2];
  size_t boff[2];
  unsigned ldsoff[2];
#pragma unroll
  for (int p = 0; p < 2; ++p) {
    const int row = wid * 32 + p * 16 + (lane >> 2);
    const int ch = lane & 3;
    // A: fp32 source (row pitch 384 floats), dest = swizzled LDS chunk
    xp[p] = xf + (size_t)(m0 + row) * Cc + ch * 8;
    xlds[p] = row * 64 + (((ch ^ (row >> 1)) & 3) << 4);
    // B: bf16 weights, pre-swizzled source, linear LDS dest
    const int gs = ch ^ ((row >> 1) & 3);
    boff[p] = (size_t)(n0 + row) * 768 + gs * 16;
    ldsoff[p] = wid * 2048 + p * 1024;
  }

  f32x4 acc[4][4] = {};  // [i = N chunk][j = M chunk]

  for (int kb = 0; kb < 12; ++kb) {
    if (kb) __syncthreads();
    // B: async global->LDS (issue first, overlaps with A conversion)
#pragma unroll
    for (int p = 0; p < 2; ++p)
      gload16(wB + boff[p] + kb * 64, Bs + ldsoff[p]);
    // A: fp32 load -> bf16 pack -> swizzled ds_write
#pragma unroll
    for (int p = 0; p < 2; ++p) {
      const float4 a = *(const float4*)(xp[p] + kb * 32);
      const float4 b = *(const float4*)(xp[p] + kb * 32 + 4);
      union { bf16x8 v; unsigned u[4]; } t;
      t.u[0] = cvt_pk_bf16(a.x, a.y); t.u[1] = cvt_pk_bf16(a.z, a.w);
      t.u[2] = cvt_pk_bf16(b.x, b.y); t.u[3] = cvt_pk_bf16(b.z, b.w);
      *(bf16x8*)(As + xlds[p]) = t.v;
    }
    __syncthreads();
    bf16x8 tfr[4], wfr[4];
#pragma unroll
    for (int i = 0; i < 4; ++i) {
      const int ar = wm * 64 + i * 16 + q;  // token rows
      tfr[i] = *(const bf16x8*)(As + ar * 64 + ((g ^ ((ar >> 1) & 3)) << 4));
      const int br = wn * 64 + i * 16 + q;  // weight rows
      wfr[i] = *(const bf16x8*)(Bs + br * 64 + ((g ^ ((br >> 1) & 3)) << 4));
    }
#pragma unroll
    for (int i = 0; i < 4; ++i)
#pragma unroll
      for (int j = 0; j < 4; ++j)
        acc[i][j] = __builtin_amdgcn_mfma_f32_16x16x32_bf16(wfr[i], tfr[j],
                                                            acc[i][j], 0, 0, 0);
  }

  const float QS = SCALE * LOG2E;
#pragma unroll
  for (int j = 0; j < 4; ++j) {
    const int t = m0 + wm * 64 + j * 16 + q;  // token id (< 15488, guard-free)
    const int bt = t / NPOS, pos = t - bt * NPOS;
    const int h = pos / Ww, w = pos - h * Ww;
    const int b = bt >> 2, tt = bt & 3;
    const int hq = h / 10, wq = w / 10;
    const int kk = tt * 100 + (h - hq * 10) * 10 + (w - wq * 10);
    const int bw = b * NWIN + hq * 5 + wq;
#pragma unroll
    for (int i = 0; i < 4; ++i) {
      const int col = n0 + wn * 64 + i * 16 + 4 * g;
      const int which = col / Cc;
      const int head = (col - which * Cc) >> 5;
      const int d4 = col & 31;
      ushort_t* pl = which == 0 ? qpl : (which == 1 ? kpl : vpl);
      const float scl = which == 0 ? QS : 1.0f;
      uint2 st;
      st.x = cvt_pk_bf16(acc[i][j][0] * scl, acc[i][j][1] * scl);
      st.y = cvt_pk_bf16(acc[i][j][2] * scl, acc[i][j][3] * scl);
      *(uint2*)(pl + ((size_t)(bw * NH + head) * NTP + kk) * HD + d4) = st;
    }
  }
}

// ---------------------------------------------------------------------------
// K2: attention on contiguous per-(bw,head) planes. 600 blocks x 448 thr
// (7 waves): 4 blocks/CU -> whole grid co-resident in one round (no tail).
// Each wave walks query tiles {wid, wid+7}; V^T staged once in swizzled LDS;
// K L1-resident on the second pass. Swapped QK^T, no-max in-register softmax
// (scores provably tiny), cvt_pk+permlane P relayout, setprio (T5).
// ---------------------------------------------------------------------------
__global__ __launch_bounds__(448) void attn_mfma(
    const ushort_t* __restrict__ qpl, const ushort_t* __restrict__ kpl,
    const ushort_t* __restrict__ vpl, ushort_t* __restrict__ aout) {
  __shared__ __align__(16) unsigned char Vt[32 * 896];

  const int wh = blockIdx.x;                   // plane index = bw*12+head
  const int head = wh % NH, bw = wh / NH;
  const int b = bw / NWIN, win = bw % NWIN, hi5 = win / 5, wi5 = win % 5;

  const int tid = threadIdx.x, lane = tid & 63, wid = tid >> 6;
  const int l31 = lane & 31, hi = lane >> 5;

  const ushort_t* qbase = qpl + (size_t)wh * (NTP * HD);
  const ushort_t* kbase = kpl + (size_t)wh * (NTP * HD);
  const ushort_t* vbase = vpl + (size_t)wh * (NTP * HD);

  // ---- stage V^T (contiguous reads; transposed swizzled writes) ----
  for (int slot = tid; slot < 1664; slot += 448) {
    const int key = slot >> 2, dblk = (slot & 3) * 8;
    union { bf16x8 v; ushort_t u[8]; } t;
    t.v = *(const bf16x8*)(vbase + (size_t)key * HD + dblk);
    const int kc = key >> 3, klo = key & 7;
#pragma unroll
    for (int j = 0; j < 8; ++j) {
      const int d = dblk + j;
      const int f = (d & 7) ^ ((d >> 3) & 3);
      *(ushort_t*)(Vt + d * 896 + ((kc ^ f) << 4) + klo * 2) = t.u[j];
    }
  }
  __syncthreads();

  const int fv = (l31 & 7) ^ ((l31 >> 3) & 3);  // V^T read swizzle for d=l31
  const unsigned char* vrow = Vt + l31 * 896;

  for (int tile = wid; tile < 13; tile += 7) {
    const int qrow = tile * 32 + l31;            // 0..415
    const ushort_t* qp = qbase + (size_t)qrow * HD;
    const bf16x8 qfa = *(const bf16x8*)(qp + hi * 8);
    const bf16x8 qfb = *(const bf16x8*)(qp + 16 + hi * 8);

    unsigned koff = (unsigned)l31 * HD;
    bf16x8 kf0 = *(const bf16x8*)(kbase + koff + hi * 8);
    bf16x8 kf1 = *(const bf16x8*)(kbase + koff + 16 + hi * 8);

    f32x16 o = {};
    float lpart = 0.f;

    for (int c = 0; c < 13; ++c) {
      f32x16 s = {};
      __builtin_amdgcn_s_setprio(1);
      s = __builtin_amdgcn_mfma_f32_32x32x16_bf16(kf0, qfa, s, 0, 0, 0);
      s = __builtin_amdgcn_mfma_f32_32x32x16_bf16(kf1, qfb, s, 0, 0, 0);
      __builtin_amdgcn_s_setprio(0);

      if (c < 12) {  // prefetch next chunk (planes padded to 416 rows)
        koff += 32u * HD;
        kf0 = *(const bf16x8*)(kbase + koff + hi * 8);
        kf1 = *(const bf16x8*)(kbase + koff + 16 + hi * 8);
      }

      if (c == 12) {  // keys 400..415 = tile rows 16..31 = regs 8..15 -> p=0
#pragma unroll
        for (int r = 8; r < 16; ++r) s[r] = -1e30f;
      }

      // ---- p = exp2(s) (no max subtraction), partial denominator ----
      float e[16];
#pragma unroll
      for (int r = 0; r < 16; ++r) e[r] = __builtin_amdgcn_exp2f(s[r]);
      lpart += ((e[0] + e[1]) + (e[2] + e[3])) + ((e[4] + e[5]) + (e[6] + e[7])) +
               (((e[8] + e[9]) + (e[10] + e[11])) +
                ((e[12] + e[13]) + (e[14] + e[15])));

      // ---- P^T -> bf16 B-frags (cvt_pk + permlane32_swap) ----
      unsigned w0 = cvt_pk_bf16(e[0], e[1]),   w1 = cvt_pk_bf16(e[2], e[3]);
      unsigned w2 = cvt_pk_bf16(e[4], e[5]),   w3 = cvt_pk_bf16(e[6], e[7]);
      unsigned w4 = cvt_pk_bf16(e[8], e[9]),   w5 = cvt_pk_bf16(e[10], e[11]);
      unsigned w6 = cvt_pk_bf16(e[12], e[13]), w7 = cvt_pk_bf16(e[14], e[15]);
      asm volatile("v_permlane32_swap_b32 %0, %1" : "+v"(w0), "+v"(w2));
      asm volatile("v_permlane32_swap_b32 %0, %1" : "+v"(w1), "+v"(w3));
      asm volatile("v_permlane32_swap_b32 %0, %1" : "+v"(w4), "+v"(w6));
      asm volatile("v_permlane32_swap_b32 %0, %1" : "+v"(w5), "+v"(w7));
      union { bf16x8 v; unsigned u[4]; } p0, p1;
      p0.u[0] = w0; p0.u[1] = w1; p0.u[2] = w2; p0.u[3] = w3;
      p1.u[0] = w4; p1.u[1] = w5; p1.u[2] = w6; p1.u[3] = w7;

      // ---- PV: O^T += V^T @ P^T ----
      const bf16x8 vf0 = *(const bf16x8*)(vrow + (((4 * c + hi) ^ fv) << 4));
      const bf16x8 vf1 = *(const bf16x8*)(vrow + (((4 * c + 2 + hi) ^ fv) << 4));
      __builtin_amdgcn_s_setprio(1);
      o = __builtin_amdgcn_mfma_f32_32x32x16_bf16(vf0, p0.v, o, 0, 0, 0);
      o = __builtin_amdgcn_mfma_f32_32x32x16_bf16(vf1, p1.v, o, 0, 0, 0);
      __builtin_amdgcn_s_setprio(0);
    }

    lpart += __shfl_xor(lpart, 32);

    // ---- epilogue: normalize, store bf16 to [token][384] ----
    {
      const int tt = qrow / 100, rem = qrow - tt * 100;
      const int hh = rem / 10, ww2 = rem - hh * 10;
      const int h = hi5 * 10 + hh, w = wi5 * 10 + ww2;
      if (qrow < NT && h < Hh && w < Ww) {
        const int qtok = (b * Tt + tt) * NPOS + h * Ww + w;
        ushort_t* dst = aout + (size_t)qtok * Cc + head * HD;
        const float inv = 1.0f / lpart;
#pragma unroll
        for (int g4 = 0; g4 < 4; ++g4) {
          unsigned lo  = cvt_pk_bf16(o[4 * g4 + 0] * inv, o[4 * g4 + 1] * inv);
          unsigned hi2 = cvt_pk_bf16(o[4 * g4 + 2] * inv, o[4 * g4 + 3] * inv);
          uint2 st; st.x = lo; st.y = hi2;
          *(uint2*)(dst + 8 * g4 + 4 * hi) = st;
        }
      }
    }
  }
}

// ---------------------------------------------------------------------------
// K3: projection GEMM [15488 x 384] @ [384 x 384]^T + bias -> fp32 out.
// Swapped operands: D-rows = 4 consecutive N-cols -> float4 stores.
// ---------------------------------------------------------------------------
__global__ __launch_bounds__(256) void proj_mfma(
    const ushort_t* __restrict__ ab, const ushort_t* __restrict__ pw,
    const float* __restrict__ bias, float* __restrict__ out) {
  __shared__ __align__(16) unsigned char As[8192];
  __shared__ __align__(16) unsigned char Bs[8192];
  const int nt = blockIdx.x, mt = blockIdx.y;
  const int tid = threadIdx.x, lane = tid & 63, wid = tid >> 6;
  const int wm = wid >> 1, wn = wid & 1;
  const int g = lane >> 4, q = lane & 15;
  const int m0 = mt * 128, n0 = nt * 128;

  const unsigned char* aB = (const unsigned char*)ab;
  const unsigned char* wB = (const unsigned char*)pw;

  size_t aoff[2], boff[2];
  unsigned ldsoff[2];
#pragma unroll
  for (int p = 0; p < 2; ++p) {
    const int row = wid * 32 + p * 16 + (lane >> 2);
    const int gs = (lane & 3) ^ ((row >> 1) & 3);
    aoff[p] = (size_t)(m0 + row) * 768 + gs * 16;
    boff[p] = (size_t)(n0 + row) * 768 + gs * 16;
    ldsoff[p] = wid * 2048 + p * 1024;
  }

  f32x4 acc[4][4] = {};  // [i = N chunk][j = M chunk]

  for (int kb = 0; kb < 12; ++kb) {
    if (kb) __syncthreads();
#pragma unroll
    for (int p = 0; p < 2; ++p) {
      gload16(aB + aoff[p] + kb * 64, As + ldsoff[p]);
      gload16(wB + boff[p] + kb * 64, Bs + ldsoff[p]);
    }
    __syncthreads();
    bf16x8 tfr[4], wfr[4];
#pragma unroll
    for (int i = 0; i < 4; ++i) {
      const int ar = wm * 64 + i * 16 + q;
      tfr[i] = *(const bf16x8*)(As + ar * 64 + ((g ^ ((ar >> 1) & 3)) << 4));
      const int br = wn * 64 + i * 16 + q;
      wfr[i] = *(const bf16x8*)(Bs + br * 64 + ((g ^ ((br >> 1) & 3)) << 4));
    }
#pragma unroll
    for (int i = 0; i < 4; ++i)
#pragma unroll
      for (int j = 0; j < 4; ++j)
        acc[i][j] = __builtin_amdgcn_mfma_f32_16x16x32_bf16(wfr[i], tfr[j],
                                                            acc[i][j], 0, 0, 0);
  }

#pragma unroll
  for (int j = 0; j < 4; ++j) {
    const int t = m0 + wm * 64 + j * 16 + q;
#pragma unroll
    for (int i = 0; i < 4; ++i) {
      const int col = n0 + wn * 64 + i * 16 + 4 * g;
      const float4 bb = *(const float4*)(bias + col);
      float4 st;
      st.x = acc[i][j][0] + bb.x;
      st.y = acc[i][j][1] + bb.y;
      st.z = acc[i][j][2] + bb.z;
      st.w = acc[i][j][3] + bb.w;
      *(float4*)(out + (size_t)t * Cc + col) = st;
    }
  }
}

// ---------------------------------------------------------------------------
extern "C" void kernel_launch(void* const* d_in, const int* in_sizes, int n_in,
                              void* d_out, int out_size, void* d_ws,
                              size_t ws_size, hipStream_t stream) {
  const float* x      = (const float*)d_in[0];
  const float* qkv_w  = (const float*)d_in[1];
  const float* proj_w = (const float*)d_in[2];
  const float* proj_b = (const float*)d_in[3];

  ushort_t* wb    = (ushort_t*)d_ws;      // [1152][384] bf16
  ushort_t* pwb   = wb + WN;              // [384][384] bf16
  ushort_t* qpl   = pwb + PWN;            // [600][416][32] bf16 planes
  ushort_t* kpl   = qpl + PLN;
  ushort_t* vpl   = kpl + PLN;
  ushort_t* attnb = vpl + PLN;            // [15488][384] bf16
  // total ~61 MB of d_ws

  constexpr int TOT8 = (int)((WN + PWN) / 8);
  constexpr int ZTOT = 50 * NTP * NH;
  conv_wz<<<(TOT8 + ZTOT + 255) / 256, 256, 0, stream>>>(qkv_w, proj_w, wb,
                                                         pwb, kpl, vpl);
  qkv_mfma<<<1089, 256, 0, stream>>>(x, wb, qpl, kpl, vpl);
  attn_mfma<<<600, 448, 0, stream>>>(qpl, kpl, vpl, attnb);
  proj_mfma<<<dim3(3, 121), 256, 0, stream>>>(attnb, pwb, proj_b, (float*)d_out);
}

// Round 13
// 87.964 us; speedup vs baseline: 1.0497x; 1.0497x over previous
//
#include <hip/hip_runtime.h>
#include <cstddef>

typedef __attribute__((ext_vector_type(8))) short bf16x8;
typedef __attribute__((ext_vector_type(4))) float f32x4;
typedef __attribute__((ext_vector_type(16))) float f32x16;
typedef unsigned short ushort_t;

namespace {
constexpr int Tt = 4, Hh = 44, Ww = 44, Cc = 384, NH = 12, HD = 32;
constexpr int NWIN = 25, NT = 400, NTP = 416, NPOS = Hh * Ww;
constexpr int NTOK = 2 * Tt * NPOS;                 // 15488 = 121*128
constexpr float SCALE = 0.17677669529663687f;       // 1/sqrt(32)
constexpr float LOG2E = 1.4426950408889634f;
constexpr size_t XN  = (size_t)NTOK * Cc;           // 5,947,392
constexpr size_t WN  = (size_t)3 * Cc * Cc;         // 442,368
constexpr size_t PWN = (size_t)Cc * Cc;             // 147,456
constexpr size_t PLN = (size_t)600 * NTP * HD;      // 7,987,200 per plane
}

__device__ __forceinline__ ushort_t f2bf(float f) {
  unsigned u = __builtin_bit_cast(unsigned, f);
  u += 0x7fffu + ((u >> 16) & 1u);  // RNE
  return (ushort_t)(u >> 16);
}

__device__ __forceinline__ unsigned cvt_pk_bf16(float a, float b) {
  unsigned r;
  asm volatile("v_cvt_pk_bf16_f32 %0, %1, %2" : "=v"(r) : "v"(a), "v"(b));
  return r;  // lo16 = bf16(a), hi16 = bf16(b)
}

// async global->LDS, 16B per lane; LDS dest = wave-uniform base + lane*16
__device__ __forceinline__ void gload16(const void* g, void* l) {
  __builtin_amdgcn_global_load_lds(
      (const __attribute__((address_space(1))) unsigned int*)g,
      (__attribute__((address_space(3))) unsigned int*)l, 16, 0, 0);
}

// ---------------------------------------------------------------------------
// K0: fp32->bf16 conversion of x, qkv_w, proj_w PLUS zero-fill of invalid /
// pad rows in the K and V windowed planes (reference semantics: padded
// positions contribute zero K rows (score 0 -> exp(0)=1 in the denominator)
// and zero V rows). Q plane needs no fill: invalid query outputs are never
// stored, and poison bf16 (0xAAAA ~ -3e-13) is numerically benign.
// ---------------------------------------------------------------------------
__global__ __launch_bounds__(256) void conv_all(
    const float* __restrict__ x, const float* __restrict__ w1,
    const float* __restrict__ w2, ushort_t* __restrict__ xo,
    ushort_t* __restrict__ w1o, ushort_t* __restrict__ w2o,
    ushort_t* __restrict__ kpl, ushort_t* __restrict__ vpl) {
  constexpr int XN8 = (int)(XN / 8), WN8 = (int)(WN / 8), PN8 = (int)(PWN / 8);
  constexpr int TOT8 = XN8 + WN8 + PN8;
  constexpr int ZTOT = 50 * NTP * NH;  // 249,600 (bw,kk,head) triples
  const int i = blockIdx.x * 256 + threadIdx.x;
  if (i < TOT8) {
    const float* s;
    ushort_t* d;
    int j;
    if (i < XN8)            { s = x;  d = xo;  j = i; }
    else if (i < XN8 + WN8) { s = w1; d = w1o; j = i - XN8; }
    else                    { s = w2; d = w2o; j = i - XN8 - WN8; }
    const float4* s4 = (const float4*)s;
    float4 a = s4[2 * j], bq = s4[2 * j + 1];
    union { bf16x8 v; ushort_t u[8]; } o;
    o.u[0] = f2bf(a.x);  o.u[1] = f2bf(a.y);  o.u[2] = f2bf(a.z);  o.u[3] = f2bf(a.w);
    o.u[4] = f2bf(bq.x); o.u[5] = f2bf(bq.y); o.u[6] = f2bf(bq.z); o.u[7] = f2bf(bq.w);
    ((bf16x8*)d)[j] = o.v;
  } else if (i < TOT8 + ZTOT) {
    const int j = i - TOT8;
    const int pair = j / NH, head = j - pair * NH;
    const int bw = pair / NTP, kk = pair - bw * NTP;
    const int win = bw % NWIN, hi5 = win / 5, wi5 = win % 5;
    bool fill;
    if (kk >= NT) {
      fill = true;
    } else {
      const int rem = kk % 100;
      const int hh = rem / 10, ww2 = rem - hh * 10;
      fill = (hi5 == 4 && hh >= 4) || (wi5 == 4 && ww2 >= 4);
    }
    if (fill) {
      const size_t off = ((size_t)(bw * NH + head) * NTP + kk) * HD;
      bf16x8 z;
      z[0]=0;z[1]=0;z[2]=0;z[3]=0;z[4]=0;z[5]=0;z[6]=0;z[7]=0;
#pragma unroll
      for (int p = 0; p < 4; ++p) {
        ((bf16x8*)(kpl + off))[p] = z;
        ((bf16x8*)(vpl + off))[p] = z;
      }
    }
  }
}

// ---------------------------------------------------------------------------
// K1: dense QKV GEMM [15488 x 384] @ [384 x 1152]^T, m97 structure (128x128
// tile, BK=32, global_load_lds 16B, pre-swizzled source). Linear grid 1089
// with bijective XCD-chunk swizzle (q=136, r=1): each XCD gets 136
// contiguous work items -> shared A-panels L2-resident. Epilogue: direct
// uint2 scatter to window planes (VGPR 28, occupancy ~67%). Q pre-scaled by
// SCALE*LOG2E.
// ---------------------------------------------------------------------------
__global__ __launch_bounds__(256) void qkv_mfma(
    const ushort_t* __restrict__ xb, const ushort_t* __restrict__ wb,
    ushort_t* __restrict__ qpl, ushort_t* __restrict__ kpl,
    ushort_t* __restrict__ vpl) {
  __shared__ __align__(16) unsigned char As[8192];
  __shared__ __align__(16) unsigned char Bs[8192];
  // bijective XCD-chunk swizzle over 1089 work items (q=136, r=1)
  const unsigned bid = blockIdx.x;
  const unsigned xcd = bid & 7u, slot = bid >> 3;
  const unsigned wgid = (xcd == 0 ? 0u : 137u + (xcd - 1u) * 136u) + slot;
  const int nt = wgid % 9, mt = wgid / 9;
  const int tid = threadIdx.x, lane = tid & 63, wid = tid >> 6;
  const int wm = wid >> 1, wn = wid & 1;
  const int g = lane >> 4, q = lane & 15;
  const int m0 = mt * 128, n0 = nt * 128;

  const unsigned char* xB = (const unsigned char*)xb;
  const unsigned char* wB = (const unsigned char*)wb;

  size_t aoff[2], boff[2];
  unsigned ldsoff[2];
#pragma unroll
  for (int p = 0; p < 2; ++p) {
    const int row = wid * 32 + p * 16 + (lane >> 2);
    const int gs = (lane & 3) ^ ((row >> 1) & 3);
    aoff[p] = (size_t)(m0 + row) * 768 + gs * 16;
    boff[p] = (size_t)(n0 + row) * 768 + gs * 16;
    ldsoff[p] = wid * 2048 + p * 1024;
  }

  f32x4 acc[4][4] = {};  // [i = N chunk][j = M chunk]

  for (int kb = 0; kb < 12; ++kb) {
    if (kb) __syncthreads();
#pragma unroll
    for (int p = 0; p < 2; ++p) {
      gload16(xB + aoff[p] + kb * 64, As + ldsoff[p]);
      gload16(wB + boff[p] + kb * 64, Bs + ldsoff[p]);
    }
    __syncthreads();
    bf16x8 tfr[4], wfr[4];
#pragma unroll
    for (int i = 0; i < 4; ++i) {
      const int ar = wm * 64 + i * 16 + q;  // token rows
      tfr[i] = *(const bf16x8*)(As + ar * 64 + ((g ^ ((ar >> 1) & 3)) << 4));
      const int br = wn * 64 + i * 16 + q;  // weight rows
      wfr[i] = *(const bf16x8*)(Bs + br * 64 + ((g ^ ((br >> 1) & 3)) << 4));
    }
#pragma unroll
    for (int i = 0; i < 4; ++i)
#pragma unroll
      for (int j = 0; j < 4; ++j)
        acc[i][j] = __builtin_amdgcn_mfma_f32_16x16x32_bf16(wfr[i], tfr[j],
                                                            acc[i][j], 0, 0, 0);
  }

  const float QS = SCALE * LOG2E;
#pragma unroll
  for (int j = 0; j < 4; ++j) {
    const int t = m0 + wm * 64 + j * 16 + q;  // token id (< 15488, guard-free)
    const int bt = t / NPOS, pos = t - bt * NPOS;
    const int h = pos / Ww, w = pos - h * Ww;
    const int b = bt >> 2, tt = bt & 3;
    const int hq = h / 10, wq = w / 10;
    const int kk = tt * 100 + (h - hq * 10) * 10 + (w - wq * 10);
    const int bw = b * NWIN + hq * 5 + wq;
#pragma unroll
    for (int i = 0; i < 4; ++i) {
      const int col = n0 + wn * 64 + i * 16 + 4 * g;
      const int which = col / Cc;
      const int head = (col - which * Cc) >> 5;
      const int d4 = col & 31;
      ushort_t* pl = which == 0 ? qpl : (which == 1 ? kpl : vpl);
      const float scl = which == 0 ? QS : 1.0f;
      uint2 st;
      st.x = cvt_pk_bf16(acc[i][j][0] * scl, acc[i][j][1] * scl);
      st.y = cvt_pk_bf16(acc[i][j][2] * scl, acc[i][j][3] * scl);
      *(uint2*)(pl + ((size_t)(bw * NH + head) * NTP + kk) * HD + d4) = st;
    }
  }
}

// ---------------------------------------------------------------------------
// K2: attention on contiguous per-(bw,head) planes. 600 blocks x 448 thr
// (7 waves): 4 blocks/CU (LDS 28KB, 28 waves/CU) -> all 600 blocks fit in
// ONE co-resident round (capacity 1024): no inter-CU scheduling tail.
// Each wave walks query tiles {wid, wid+7} sequentially; V^T staged once in
// swizzled LDS, shared by both passes; K L1-resident on the second pass.
// Q read linearly from its window plane (no decode in the loop). Swapped
// QK^T, no-max in-register softmax, cvt_pk+permlane P relayout, setprio (T5).
// ---------------------------------------------------------------------------
__global__ __launch_bounds__(448) void attn_mfma(
    const ushort_t* __restrict__ qpl, const ushort_t* __restrict__ kpl,
    const ushort_t* __restrict__ vpl, ushort_t* __restrict__ aout) {
  __shared__ __align__(16) unsigned char Vt[32 * 896];

  const int wh = blockIdx.x;                   // plane index = bw*12+head
  const int head = wh % NH, bw = wh / NH;
  const int b = bw / NWIN, win = bw % NWIN, hi5 = win / 5, wi5 = win % 5;

  const int tid = threadIdx.x, lane = tid & 63, wid = tid >> 6;
  const int l31 = lane & 31, hi = lane >> 5;

  const ushort_t* qbase = qpl + (size_t)wh * (NTP * HD);
  const ushort_t* kbase = kpl + (size_t)wh * (NTP * HD);
  const ushort_t* vbase = vpl + (size_t)wh * (NTP * HD);

  // ---- stage V^T (contiguous reads; transposed swizzled writes) ----
  for (int slot = tid; slot < 1664; slot += 448) {
    const int key = slot >> 2, dblk = (slot & 3) * 8;
    union { bf16x8 v; ushort_t u[8]; } t;
    t.v = *(const bf16x8*)(vbase + (size_t)key * HD + dblk);
    const int kc = key >> 3, klo = key & 7;
#pragma unroll
    for (int j = 0; j < 8; ++j) {
      const int d = dblk + j;
      const int f = (d & 7) ^ ((d >> 3) & 3);
      *(ushort_t*)(Vt + d * 896 + ((kc ^ f) << 4) + klo * 2) = t.u[j];
    }
  }
  __syncthreads();

  const int fv = (l31 & 7) ^ ((l31 >> 3) & 3);  // V^T read swizzle for d=l31
  const unsigned char* vrow = Vt + l31 * 896;

  for (int tile = wid; tile < 13; tile += 7) {
    const int qrow = tile * 32 + l31;            // 0..415
    const ushort_t* qp = qbase + (size_t)qrow * HD;
    const bf16x8 qfa = *(const bf16x8*)(qp + hi * 8);
    const bf16x8 qfb = *(const bf16x8*)(qp + 16 + hi * 8);

    unsigned koff = (unsigned)l31 * HD;
    bf16x8 kf0 = *(const bf16x8*)(kbase + koff + hi * 8);
    bf16x8 kf1 = *(const bf16x8*)(kbase + koff + 16 + hi * 8);

    f32x16 o = {};
    float lpart = 0.f;

    for (int c = 0; c < 13; ++c) {
      f32x16 s = {};
      __builtin_amdgcn_s_setprio(1);
      s = __builtin_amdgcn_mfma_f32_32x32x16_bf16(kf0, qfa, s, 0, 0, 0);
      s = __builtin_amdgcn_mfma_f32_32x32x16_bf16(kf1, qfb, s, 0, 0, 0);
      __builtin_amdgcn_s_setprio(0);

      if (c < 12) {  // prefetch next chunk (planes padded to 416 rows)
        koff += 32u * HD;
        kf0 = *(const bf16x8*)(kbase + koff + hi * 8);
        kf1 = *(const bf16x8*)(kbase + koff + 16 + hi * 8);
      }

      if (c == 12) {  // keys 400..415 = tile rows 16..31 = regs 8..15 -> p=0
#pragma unroll
        for (int r = 8; r < 16; ++r) s[r] = -1e30f;
      }

      // ---- p = exp2(s) (no max subtraction), partial denominator ----
      float e[16];
#pragma unroll
      for (int r = 0; r < 16; ++r) e[r] = __builtin_amdgcn_exp2f(s[r]);
      lpart += ((e[0] + e[1]) + (e[2] + e[3])) + ((e[4] + e[5]) + (e[6] + e[7])) +
               (((e[8] + e[9]) + (e[10] + e[11])) +
                ((e[12] + e[13]) + (e[14] + e[15])));

      // ---- P^T -> bf16 B-frags (cvt_pk + permlane32_swap) ----
      unsigned w0 = cvt_pk_bf16(e[0], e[1]),   w1 = cvt_pk_bf16(e[2], e[3]);
      unsigned w2 = cvt_pk_bf16(e[4], e[5]),   w3 = cvt_pk_bf16(e[6], e[7]);
      unsigned w4 = cvt_pk_bf16(e[8], e[9]),   w5 = cvt_pk_bf16(e[10], e[11]);
      unsigned w6 = cvt_pk_bf16(e[12], e[13]), w7 = cvt_pk_bf16(e[14], e[15]);
      asm volatile("v_permlane32_swap_b32 %0, %1" : "+v"(w0), "+v"(w2));
      asm volatile("v_permlane32_swap_b32 %0, %1" : "+v"(w1), "+v"(w3));
      asm volatile("v_permlane32_swap_b32 %0, %1" : "+v"(w4), "+v"(w6));
      asm volatile("v_permlane32_swap_b32 %0, %1" : "+v"(w5), "+v"(w7));
      union { bf16x8 v; unsigned u[4]; } p0, p1;
      p0.u[0] = w0; p0.u[1] = w1; p0.u[2] = w2; p0.u[3] = w3;
      p1.u[0] = w4; p1.u[1] = w5; p1.u[2] = w6; p1.u[3] = w7;

      // ---- PV: O^T += V^T @ P^T ----
      const bf16x8 vf0 = *(const bf16x8*)(vrow + (((4 * c + hi) ^ fv) << 4));
      const bf16x8 vf1 = *(const bf16x8*)(vrow + (((4 * c + 2 + hi) ^ fv) << 4));
      __builtin_amdgcn_s_setprio(1);
      o = __builtin_amdgcn_mfma_f32_32x32x16_bf16(vf0, p0.v, o, 0, 0, 0);
      o = __builtin_amdgcn_mfma_f32_32x32x16_bf16(vf1, p1.v, o, 0, 0, 0);
      __builtin_amdgcn_s_setprio(0);
    }

    lpart += __shfl_xor(lpart, 32);

    // ---- epilogue: normalize, store bf16 to [token][384] ----
    {
      const int tt = qrow / 100, rem = qrow - tt * 100;
      const int hh = rem / 10, ww2 = rem - hh * 10;
      const int h = hi5 * 10 + hh, w = wi5 * 10 + ww2;
      if (qrow < NT && h < Hh && w < Ww) {
        const int qtok = (b * Tt + tt) * NPOS + h * Ww + w;
        ushort_t* dst = aout + (size_t)qtok * Cc + head * HD;
        const float inv = 1.0f / lpart;
#pragma unroll
        for (int g4 = 0; g4 < 4; ++g4) {
          unsigned lo  = cvt_pk_bf16(o[4 * g4 + 0] * inv, o[4 * g4 + 1] * inv);
          unsigned hi2 = cvt_pk_bf16(o[4 * g4 + 2] * inv, o[4 * g4 + 3] * inv);
          uint2 st; st.x = lo; st.y = hi2;
          *(uint2*)(dst + 8 * g4 + 4 * hi) = st;
        }
      }
    }
  }
}

// ---------------------------------------------------------------------------
// K3: projection GEMM [15488 x 384] @ [384 x 384]^T + bias -> fp32 out.
// Swapped operands: D-rows = 4 consecutive N-cols -> float4 stores.
// ---------------------------------------------------------------------------
__global__ __launch_bounds__(256) void proj_mfma(
    const ushort_t* __restrict__ ab, const ushort_t* __restrict__ pw,
    const float* __restrict__ bias, float* __restrict__ out) {
  __shared__ __align__(16) unsigned char As[8192];
  __shared__ __align__(16) unsigned char Bs[8192];
  const int nt = blockIdx.x, mt = blockIdx.y;
  const int tid = threadIdx.x, lane = tid & 63, wid = tid >> 6;
  const int wm = wid >> 1, wn = wid & 1;
  const int g = lane >> 4, q = lane & 15;
  const int m0 = mt * 128, n0 = nt * 128;

  const unsigned char* aB = (const unsigned char*)ab;
  const unsigned char* wB = (const unsigned char*)pw;

  size_t aoff[2], boff[2];
  unsigned ldsoff[2];
#pragma unroll
  for (int p = 0; p < 2; ++p) {
    const int row = wid * 32 + p * 16 + (lane >> 2);
    const int gs = (lane & 3) ^ ((row >> 1) & 3);
    aoff[p] = (size_t)(m0 + row) * 768 + gs * 16;
    boff[p] = (size_t)(n0 + row) * 768 + gs * 16;
    ldsoff[p] = wid * 2048 + p * 1024;
  }

  f32x4 acc[4][4] = {};  // [i = N chunk][j = M chunk]

  for (int kb = 0; kb < 12; ++kb) {
    if (kb) __syncthreads();
#pragma unroll
    for (int p = 0; p < 2; ++p) {
      gload16(aB + aoff[p] + kb * 64, As + ldsoff[p]);
      gload16(wB + boff[p] + kb * 64, Bs + ldsoff[p]);
    }
    __syncthreads();
    bf16x8 tfr[4], wfr[4];
#pragma unroll
    for (int i = 0; i < 4; ++i) {
      const int ar = wm * 64 + i * 16 + q;
      tfr[i] = *(const bf16x8*)(As + ar * 64 + ((g ^ ((ar >> 1) & 3)) << 4));
      const int br = wn * 64 + i * 16 + q;
      wfr[i] = *(const bf16x8*)(Bs + br * 64 + ((g ^ ((br >> 1) & 3)) << 4));
    }
#pragma unroll
    for (int i = 0; i < 4; ++i)
#pragma unroll
      for (int j = 0; j < 4; ++j)
        acc[i][j] = __builtin_amdgcn_mfma_f32_16x16x32_bf16(wfr[i], tfr[j],
                                                            acc[i][j], 0, 0, 0);
  }

#pragma unroll
  for (int j = 0; j < 4; ++j) {
    const int t = m0 + wm * 64 + j * 16 + q;
#pragma unroll
    for (int i = 0; i < 4; ++i) {
      const int col = n0 + wn * 64 + i * 16 + 4 * g;
      const float4 bb = *(const float4*)(bias + col);
      float4 st;
      st.x = acc[i][j][0] + bb.x;
      st.y = acc[i][j][1] + bb.y;
      st.z = acc[i][j][2] + bb.z;
      st.w = acc[i][j][3] + bb.w;
      *(float4*)(out + (size_t)t * Cc + col) = st;
    }
  }
}

// ---------------------------------------------------------------------------
extern "C" void kernel_launch(void* const* d_in, const int* in_sizes, int n_in,
                              void* d_out, int out_size, void* d_ws,
                              size_t ws_size, hipStream_t stream) {
  const float* x      = (const float*)d_in[0];
  const float* qkv_w  = (const float*)d_in[1];
  const float* proj_w = (const float*)d_in[2];
  const float* proj_b = (const float*)d_in[3];

  ushort_t* xb    = (ushort_t*)d_ws;      // [15488][384] bf16
  ushort_t* wb    = xb + XN;              // [1152][384] bf16
  ushort_t* pwb   = wb + WN;              // [384][384] bf16
  ushort_t* qpl   = pwb + PWN;            // [600][416][32] bf16 planes
  ushort_t* kpl   = qpl + PLN;
  ushort_t* vpl   = kpl + PLN;
  ushort_t* attnb = vpl + PLN;            // [15488][384] bf16
  // total ~73 MB of d_ws

  constexpr int TOT8 = (int)((XN + WN + PWN) / 8);
  constexpr int ZTOT = 50 * NTP * NH;
  conv_all<<<(TOT8 + ZTOT + 255) / 256, 256, 0, stream>>>(
      x, qkv_w, proj_w, xb, wb, pwb, kpl, vpl);
  qkv_mfma<<<1089, 256, 0, stream>>>(xb, wb, qpl, kpl, vpl);
  attn_mfma<<<600, 448, 0, stream>>>(qpl, kpl, vpl, attnb);
  proj_mfma<<<dim3(3, 121), 256, 0, stream>>>(attnb, pwb, proj_b, (float*)d_out);
}

// Round 14
// 85.691 us; speedup vs baseline: 1.0775x; 1.0265x over previous
//
#include <hip/hip_runtime.h>
#include <cstddef>

typedef __attribute__((ext_vector_type(8))) short bf16x8;
typedef __attribute__((ext_vector_type(4))) float f32x4;
typedef __attribute__((ext_vector_type(16))) float f32x16;
typedef unsigned short ushort_t;

namespace {
constexpr int Tt = 4, Hh = 44, Ww = 44, Cc = 384, NH = 12, HD = 32;
constexpr int NWIN = 25, NT = 400, NTP = 416, NPOS = Hh * Ww;
constexpr int NTOK = 2 * Tt * NPOS;                 // 15488 = 121*128
constexpr float SCALE = 0.17677669529663687f;       // 1/sqrt(32)
constexpr float LOG2E = 1.4426950408889634f;
constexpr size_t XN  = (size_t)NTOK * Cc;           // 5,947,392
constexpr size_t WN  = (size_t)3 * Cc * Cc;         // 442,368
constexpr size_t PWN = (size_t)Cc * Cc;             // 147,456
constexpr size_t PLN = (size_t)600 * NTP * HD;      // 7,987,200 per plane
}

__device__ __forceinline__ ushort_t f2bf(float f) {
  unsigned u = __builtin_bit_cast(unsigned, f);
  u += 0x7fffu + ((u >> 16) & 1u);  // RNE
  return (ushort_t)(u >> 16);
}

__device__ __forceinline__ unsigned cvt_pk_bf16(float a, float b) {
  unsigned r;
  asm volatile("v_cvt_pk_bf16_f32 %0, %1, %2" : "=v"(r) : "v"(a), "v"(b));
  return r;  // lo16 = bf16(a), hi16 = bf16(b)
}

// async global->LDS, 16B per lane; LDS dest = wave-uniform base + lane*16
__device__ __forceinline__ void gload16(const void* g, void* l) {
  __builtin_amdgcn_global_load_lds(
      (const __attribute__((address_space(1))) unsigned int*)g,
      (__attribute__((address_space(3))) unsigned int*)l, 16, 0, 0);
}

// ---------------------------------------------------------------------------
// K0: fp32->bf16 conversion of x, qkv_w, proj_w PLUS zero-fill of invalid /
// pad rows in the K and V windowed planes (reference semantics: padded
// positions contribute zero K rows (score 0 -> exp(0)=1 in the denominator)
// and zero V rows). Q plane needs no fill: invalid query outputs are never
// stored, and poison bf16 (0xAAAA ~ -3e-13) is numerically benign.
// ---------------------------------------------------------------------------
__global__ __launch_bounds__(256) void conv_all(
    const float* __restrict__ x, const float* __restrict__ w1,
    const float* __restrict__ w2, ushort_t* __restrict__ xo,
    ushort_t* __restrict__ w1o, ushort_t* __restrict__ w2o,
    ushort_t* __restrict__ kpl, ushort_t* __restrict__ vpl) {
  constexpr int XN8 = (int)(XN / 8), WN8 = (int)(WN / 8), PN8 = (int)(PWN / 8);
  constexpr int TOT8 = XN8 + WN8 + PN8;
  constexpr int ZTOT = 50 * NTP * NH;  // 249,600 (bw,kk,head) triples
  const int i = blockIdx.x * 256 + threadIdx.x;
  if (i < TOT8) {
    const float* s;
    ushort_t* d;
    int j;
    if (i < XN8)            { s = x;  d = xo;  j = i; }
    else if (i < XN8 + WN8) { s = w1; d = w1o; j = i - XN8; }
    else                    { s = w2; d = w2o; j = i - XN8 - WN8; }
    const float4* s4 = (const float4*)s;
    float4 a = s4[2 * j], bq = s4[2 * j + 1];
    union { bf16x8 v; ushort_t u[8]; } o;
    o.u[0] = f2bf(a.x);  o.u[1] = f2bf(a.y);  o.u[2] = f2bf(a.z);  o.u[3] = f2bf(a.w);
    o.u[4] = f2bf(bq.x); o.u[5] = f2bf(bq.y); o.u[6] = f2bf(bq.z); o.u[7] = f2bf(bq.w);
    ((bf16x8*)d)[j] = o.v;
  } else if (i < TOT8 + ZTOT) {
    const int j = i - TOT8;
    const int pair = j / NH, head = j - pair * NH;
    const int bw = pair / NTP, kk = pair - bw * NTP;
    const int win = bw % NWIN, hi5 = win / 5, wi5 = win % 5;
    bool fill;
    if (kk >= NT) {
      fill = true;
    } else {
      const int rem = kk % 100;
      const int hh = rem / 10, ww2 = rem - hh * 10;
      fill = (hi5 == 4 && hh >= 4) || (wi5 == 4 && ww2 >= 4);
    }
    if (fill) {
      const size_t off = ((size_t)(bw * NH + head) * NTP + kk) * HD;
      bf16x8 z;
      z[0]=0;z[1]=0;z[2]=0;z[3]=0;z[4]=0;z[5]=0;z[6]=0;z[7]=0;
#pragma unroll
      for (int p = 0; p < 4; ++p) {
        ((bf16x8*)(kpl + off))[p] = z;
        ((bf16x8*)(vpl + off))[p] = z;
      }
    }
  }
}

// ---------------------------------------------------------------------------
// K1: dense QKV GEMM [15488 x 384] @ [384 x 1152]^T, m97 structure, BK=64:
// 6 staging phases (was 12), 32 MFMAs per compute phase. LDS 32KB (As/Bs
// 16KB, 128B row pitch = 8x16B chunks). Involution swizzle chunk^=(row&7)
// applied on gload source AND frag-read address (linear LDS dest). Linear
// grid 1089 with bijective XCD-chunk swizzle (q=136, r=1). Epilogue: direct
// uint2 scatter to window planes; Q pre-scaled by SCALE*LOG2E.
// ---------------------------------------------------------------------------
__global__ __launch_bounds__(256) void qkv_mfma(
    const ushort_t* __restrict__ xb, const ushort_t* __restrict__ wb,
    ushort_t* __restrict__ qpl, ushort_t* __restrict__ kpl,
    ushort_t* __restrict__ vpl) {
  __shared__ __align__(16) unsigned char As[16384];
  __shared__ __align__(16) unsigned char Bs[16384];
  // bijective XCD-chunk swizzle over 1089 work items (q=136, r=1)
  const unsigned bid = blockIdx.x;
  const unsigned xcd = bid & 7u, slot = bid >> 3;
  const unsigned wgid = (xcd == 0 ? 0u : 137u + (xcd - 1u) * 136u) + slot;
  const int nt = wgid % 9, mt = wgid / 9;
  const int tid = threadIdx.x, lane = tid & 63, wid = tid >> 6;
  const int wm = wid >> 1, wn = wid & 1;
  const int g = lane >> 4, q = lane & 15;
  const int m0 = mt * 128, n0 = nt * 128;

  const unsigned char* xB = (const unsigned char*)xb;
  const unsigned char* wB = (const unsigned char*)wb;

  // staging: 4 passes; pass p: wave wid covers LDS rows wid*32+p*8 .. +8
  size_t aoff[4], boff[4];
  unsigned ldsoff[4];
#pragma unroll
  for (int p = 0; p < 4; ++p) {
    const int row = wid * 32 + p * 8 + (lane >> 3);
    const int ch = lane & 7;                       // 16B chunk in 128B row
    const int gs = ch ^ (row & 7);                 // involution swizzle
    aoff[p] = (size_t)(m0 + row) * 768 + gs * 16;
    boff[p] = (size_t)(n0 + row) * 768 + gs * 16;
    ldsoff[p] = wid * 4096 + p * 1024;             // linear dest
  }

  f32x4 acc[4][4] = {};  // [i = N chunk][j = M chunk]

  for (int kb = 0; kb < 6; ++kb) {
    if (kb) __syncthreads();
#pragma unroll
    for (int p = 0; p < 4; ++p) {
      gload16(xB + aoff[p] + kb * 128, As + ldsoff[p]);
      gload16(wB + boff[p] + kb * 128, Bs + ldsoff[p]);
    }
    __syncthreads();
#pragma unroll
    for (int s = 0; s < 2; ++s) {
      bf16x8 tfr[4], wfr[4];
#pragma unroll
      for (int i = 0; i < 4; ++i) {
        const int ar = wm * 64 + i * 16 + q;  // token rows
        tfr[i] = *(const bf16x8*)(As + ar * 128 +
                                  (((s * 4 + g) ^ (ar & 7)) << 4));
        const int br = wn * 64 + i * 16 + q;  // weight rows
        wfr[i] = *(const bf16x8*)(Bs + br * 128 +
                                  (((s * 4 + g) ^ (br & 7)) << 4));
      }
#pragma unroll
      for (int i = 0; i < 4; ++i)
#pragma unroll
        for (int j = 0; j < 4; ++j)
          acc[i][j] = __builtin_amdgcn_mfma_f32_16x16x32_bf16(
              wfr[i], tfr[j], acc[i][j], 0, 0, 0);
    }
  }

  const float QS = SCALE * LOG2E;
#pragma unroll
  for (int j = 0; j < 4; ++j) {
    const int t = m0 + wm * 64 + j * 16 + q;  // token id (< 15488, guard-free)
    const int bt = t / NPOS, pos = t - bt * NPOS;
    const int h = pos / Ww, w = pos - h * Ww;
    const int b = bt >> 2, tt = bt & 3;
    const int hq = h / 10, wq = w / 10;
    const int kk = tt * 100 + (h - hq * 10) * 10 + (w - wq * 10);
    const int bw = b * NWIN + hq * 5 + wq;
#pragma unroll
    for (int i = 0; i < 4; ++i) {
      const int col = n0 + wn * 64 + i * 16 + 4 * g;
      const int which = col / Cc;
      const int head = (col - which * Cc) >> 5;
      const int d4 = col & 31;
      ushort_t* pl = which == 0 ? qpl : (which == 1 ? kpl : vpl);
      const float scl = which == 0 ? QS : 1.0f;
      uint2 st;
      st.x = cvt_pk_bf16(acc[i][j][0] * scl, acc[i][j][1] * scl);
      st.y = cvt_pk_bf16(acc[i][j][2] * scl, acc[i][j][3] * scl);
      *(uint2*)(pl + ((size_t)(bw * NH + head) * NTP + kk) * HD + d4) = st;
    }
  }
}

// ---------------------------------------------------------------------------
// K2: attention on contiguous per-(bw,head) planes. 600 blocks x 448 thr
// (7 waves): 4 blocks/CU (LDS 28KB, 28 waves/CU) -> all 600 blocks fit in
// ONE co-resident round (capacity 1024): no inter-CU scheduling tail.
// Each wave walks query tiles {wid, wid+7} sequentially; V^T staged once in
// swizzled LDS, shared by both passes; K L1-resident on the second pass.
// Q read linearly from its window plane (no decode in the loop). Swapped
// QK^T, no-max in-register softmax, cvt_pk+permlane P relayout, setprio (T5).
// ---------------------------------------------------------------------------
__global__ __launch_bounds__(448) void attn_mfma(
    const ushort_t* __restrict__ qpl, const ushort_t* __restrict__ kpl,
    const ushort_t* __restrict__ vpl, ushort_t* __restrict__ aout) {
  __shared__ __align__(16) unsigned char Vt[32 * 896];

  const int wh = blockIdx.x;                   // plane index = bw*12+head
  const int head = wh % NH, bw = wh / NH;
  const int b = bw / NWIN, win = bw % NWIN, hi5 = win / 5, wi5 = win % 5;

  const int tid = threadIdx.x, lane = tid & 63, wid = tid >> 6;
  const int l31 = lane & 31, hi = lane >> 5;

  const ushort_t* qbase = qpl + (size_t)wh * (NTP * HD);
  const ushort_t* kbase = kpl + (size_t)wh * (NTP * HD);
  const ushort_t* vbase = vpl + (size_t)wh * (NTP * HD);

  // ---- stage V^T (contiguous reads; transposed swizzled writes) ----
  for (int slot = tid; slot < 1664; slot += 448) {
    const int key = slot >> 2, dblk = (slot & 3) * 8;
    union { bf16x8 v; ushort_t u[8]; } t;
    t.v = *(const bf16x8*)(vbase + (size_t)key * HD + dblk);
    const int kc = key >> 3, klo = key & 7;
#pragma unroll
    for (int j = 0; j < 8; ++j) {
      const int d = dblk + j;
      const int f = (d & 7) ^ ((d >> 3) & 3);
      *(ushort_t*)(Vt + d * 896 + ((kc ^ f) << 4) + klo * 2) = t.u[j];
    }
  }
  __syncthreads();

  const int fv = (l31 & 7) ^ ((l31 >> 3) & 3);  // V^T read swizzle for d=l31
  const unsigned char* vrow = Vt + l31 * 896;

  for (int tile = wid; tile < 13; tile += 7) {
    const int qrow = tile * 32 + l31;            // 0..415
    const ushort_t* qp = qbase + (size_t)qrow * HD;
    const bf16x8 qfa = *(const bf16x8*)(qp + hi * 8);
    const bf16x8 qfb = *(const bf16x8*)(qp + 16 + hi * 8);

    unsigned koff = (unsigned)l31 * HD;
    bf16x8 kf0 = *(const bf16x8*)(kbase + koff + hi * 8);
    bf16x8 kf1 = *(const bf16x8*)(kbase + koff + 16 + hi * 8);

    f32x16 o = {};
    float lpart = 0.f;

    for (int c = 0; c < 13; ++c) {
      f32x16 s = {};
      __builtin_amdgcn_s_setprio(1);
      s = __builtin_amdgcn_mfma_f32_32x32x16_bf16(kf0, qfa, s, 0, 0, 0);
      s = __builtin_amdgcn_mfma_f32_32x32x16_bf16(kf1, qfb, s, 0, 0, 0);
      __builtin_amdgcn_s_setprio(0);

      if (c < 12) {  // prefetch next chunk (planes padded to 416 rows)
        koff += 32u * HD;
        kf0 = *(const bf16x8*)(kbase + koff + hi * 8);
        kf1 = *(const bf16x8*)(kbase + koff + 16 + hi * 8);
      }

      if (c == 12) {  // keys 400..415 = tile rows 16..31 = regs 8..15 -> p=0
#pragma unroll
        for (int r = 8; r < 16; ++r) s[r] = -1e30f;
      }

      // ---- p = exp2(s) (no max subtraction), partial denominator ----
      float e[16];
#pragma unroll
      for (int r = 0; r < 16; ++r) e[r] = __builtin_amdgcn_exp2f(s[r]);
      lpart += ((e[0] + e[1]) + (e[2] + e[3])) + ((e[4] + e[5]) + (e[6] + e[7])) +
               (((e[8] + e[9]) + (e[10] + e[11])) +
                ((e[12] + e[13]) + (e[14] + e[15])));

      // ---- P^T -> bf16 B-frags (cvt_pk + permlane32_swap) ----
      unsigned w0 = cvt_pk_bf16(e[0], e[1]),   w1 = cvt_pk_bf16(e[2], e[3]);
      unsigned w2 = cvt_pk_bf16(e[4], e[5]),   w3 = cvt_pk_bf16(e[6], e[7]);
      unsigned w4 = cvt_pk_bf16(e[8], e[9]),   w5 = cvt_pk_bf16(e[10], e[11]);
      unsigned w6 = cvt_pk_bf16(e[12], e[13]), w7 = cvt_pk_bf16(e[14], e[15]);
      asm volatile("v_permlane32_swap_b32 %0, %1" : "+v"(w0), "+v"(w2));
      asm volatile("v_permlane32_swap_b32 %0, %1" : "+v"(w1), "+v"(w3));
      asm volatile("v_permlane32_swap_b32 %0, %1" : "+v"(w4), "+v"(w6));
      asm volatile("v_permlane32_swap_b32 %0, %1" : "+v"(w5), "+v"(w7));
      union { bf16x8 v; unsigned u[4]; } p0, p1;
      p0.u[0] = w0; p0.u[1] = w1; p0.u[2] = w2; p0.u[3] = w3;
      p1.u[0] = w4; p1.u[1] = w5; p1.u[2] = w6; p1.u[3] = w7;

      // ---- PV: O^T += V^T @ P^T ----
      const bf16x8 vf0 = *(const bf16x8*)(vrow + (((4 * c + hi) ^ fv) << 4));
      const bf16x8 vf1 = *(const bf16x8*)(vrow + (((4 * c + 2 + hi) ^ fv) << 4));
      __builtin_amdgcn_s_setprio(1);
      o = __builtin_amdgcn_mfma_f32_32x32x16_bf16(vf0, p0.v, o, 0, 0, 0);
      o = __builtin_amdgcn_mfma_f32_32x32x16_bf16(vf1, p1.v, o, 0, 0, 0);
      __builtin_amdgcn_s_setprio(0);
    }

    lpart += __shfl_xor(lpart, 32);

    // ---- epilogue: normalize, store bf16 to [token][384] ----
    {
      const int tt = qrow / 100, rem = qrow - tt * 100;
      const int hh = rem / 10, ww2 = rem - hh * 10;
      const int h = hi5 * 10 + hh, w = wi5 * 10 + ww2;
      if (qrow < NT && h < Hh && w < Ww) {
        const int qtok = (b * Tt + tt) * NPOS + h * Ww + w;
        ushort_t* dst = aout + (size_t)qtok * Cc + head * HD;
        const float inv = 1.0f / lpart;
#pragma unroll
        for (int g4 = 0; g4 < 4; ++g4) {
          unsigned lo  = cvt_pk_bf16(o[4 * g4 + 0] * inv, o[4 * g4 + 1] * inv);
          unsigned hi2 = cvt_pk_bf16(o[4 * g4 + 2] * inv, o[4 * g4 + 3] * inv);
          uint2 st; st.x = lo; st.y = hi2;
          *(uint2*)(dst + 8 * g4 + 4 * hi) = st;
        }
      }
    }
  }
}

// ---------------------------------------------------------------------------
// K3: projection GEMM [15488 x 384] @ [384 x 384]^T + bias -> fp32 out.
// Swapped operands: D-rows = 4 consecutive N-cols -> float4 stores.
// (Unchanged BK=32 form for attribution.)
// ---------------------------------------------------------------------------
__global__ __launch_bounds__(256) void proj_mfma(
    const ushort_t* __restrict__ ab, const ushort_t* __restrict__ pw,
    const float* __restrict__ bias, float* __restrict__ out) {
  __shared__ __align__(16) unsigned char As[8192];
  __shared__ __align__(16) unsigned char Bs[8192];
  const int nt = blockIdx.x, mt = blockIdx.y;
  const int tid = threadIdx.x, lane = tid & 63, wid = tid >> 6;
  const int wm = wid >> 1, wn = wid & 1;
  const int g = lane >> 4, q = lane & 15;
  const int m0 = mt * 128, n0 = nt * 128;

  const unsigned char* aB = (const unsigned char*)ab;
  const unsigned char* wB = (const unsigned char*)pw;

  size_t aoff[2], boff[2];
  unsigned ldsoff[2];
#pragma unroll
  for (int p = 0; p < 2; ++p) {
    const int row = wid * 32 + p * 16 + (lane >> 2);
    const int gs = (lane & 3) ^ ((row >> 1) & 3);
    aoff[p] = (size_t)(m0 + row) * 768 + gs * 16;
    boff[p] = (size_t)(n0 + row) * 768 + gs * 16;
    ldsoff[p] = wid * 2048 + p * 1024;
  }

  f32x4 acc[4][4] = {};  // [i = N chunk][j = M chunk]

  for (int kb = 0; kb < 12; ++kb) {
    if (kb) __syncthreads();
#pragma unroll
    for (int p = 0; p < 2; ++p) {
      gload16(aB + aoff[p] + kb * 64, As + ldsoff[p]);
      gload16(wB + boff[p] + kb * 64, Bs + ldsoff[p]);
    }
    __syncthreads();
    bf16x8 tfr[4], wfr[4];
#pragma unroll
    for (int i = 0; i < 4; ++i) {
      const int ar = wm * 64 + i * 16 + q;
      tfr[i] = *(const bf16x8*)(As + ar * 64 + ((g ^ ((ar >> 1) & 3)) << 4));
      const int br = wn * 64 + i * 16 + q;
      wfr[i] = *(const bf16x8*)(Bs + br * 64 + ((g ^ ((br >> 1) & 3)) << 4));
    }
#pragma unroll
    for (int i = 0; i < 4; ++i)
#pragma unroll
      for (int j = 0; j < 4; ++j)
        acc[i][j] = __builtin_amdgcn_mfma_f32_16x16x32_bf16(wfr[i], tfr[j],
                                                            acc[i][j], 0, 0, 0);
  }

#pragma unroll
  for (int j = 0; j < 4; ++j) {
    const int t = m0 + wm * 64 + j * 16 + q;
#pragma unroll
    for (int i = 0; i < 4; ++i) {
      const int col = n0 + wn * 64 + i * 16 + 4 * g;
      const float4 bb = *(const float4*)(bias + col);
      float4 st;
      st.x = acc[i][j][0] + bb.x;
      st.y = acc[i][j][1] + bb.y;
      st.z = acc[i][j][2] + bb.z;
      st.w = acc[i][j][3] + bb.w;
      *(float4*)(out + (size_t)t * Cc + col) = st;
    }
  }
}

// ---------------------------------------------------------------------------
extern "C" void kernel_launch(void* const* d_in, const int* in_sizes, int n_in,
                              void* d_out, int out_size, void* d_ws,
                              size_t ws_size, hipStream_t stream) {
  const float* x      = (const float*)d_in[0];
  const float* qkv_w  = (const float*)d_in[1];
  const float* proj_w = (const float*)d_in[2];
  const float* proj_b = (const float*)d_in[3];

  ushort_t* xb    = (ushort_t*)d_ws;      // [15488][384] bf16
  ushort_t* wb    = xb + XN;              // [1152][384] bf16
  ushort_t* pwb   = wb + WN;              // [384][384] bf16
  ushort_t* qpl   = pwb + PWN;            // [600][416][32] bf16 planes
  ushort_t* kpl   = qpl + PLN;
  ushort_t* vpl   = kpl + PLN;
  ushort_t* attnb = vpl + PLN;            // [15488][384] bf16
  // total ~73 MB of d_ws

  constexpr int TOT8 = (int)((XN + WN + PWN) / 8);
  constexpr int ZTOT = 50 * NTP * NH;
  conv_all<<<(TOT8 + ZTOT + 255) / 256, 256, 0, stream>>>(
      x, qkv_w, proj_w, xb, wb, pwb, kpl, vpl);
  qkv_mfma<<<1089, 256, 0, stream>>>(xb, wb, qpl, kpl, vpl);
  attn_mfma<<<600, 448, 0, stream>>>(qpl, kpl, vpl, attnb);
  proj_mfma<<<dim3(3, 121), 256, 0, stream>>>(attnb, pwb, proj_b, (float*)d_out);
}

// Round 15
// 84.295 us; speedup vs baseline: 1.0954x; 1.0166x over previous
//
#include <hip/hip_runtime.h>
#include <cstddef>

typedef __attribute__((ext_vector_type(8))) short bf16x8;
typedef __attribute__((ext_vector_type(4))) float f32x4;
typedef __attribute__((ext_vector_type(16))) float f32x16;
typedef unsigned short ushort_t;

namespace {
constexpr int Tt = 4, Hh = 44, Ww = 44, Cc = 384, NH = 12, HD = 32;
constexpr int NWIN = 25, NT = 400, NTP = 416, NPOS = Hh * Ww;
constexpr int NTOK = 2 * Tt * NPOS;                 // 15488 = 121*128
constexpr float SCALE = 0.17677669529663687f;       // 1/sqrt(32)
constexpr float LOG2E = 1.4426950408889634f;
constexpr size_t XN  = (size_t)NTOK * Cc;           // 5,947,392
constexpr size_t WN  = (size_t)3 * Cc * Cc;         // 442,368
constexpr size_t PWN = (size_t)Cc * Cc;             // 147,456
constexpr size_t PLN = (size_t)600 * NTP * HD;      // 7,987,200 per plane
}

__device__ __forceinline__ ushort_t f2bf(float f) {
  unsigned u = __builtin_bit_cast(unsigned, f);
  u += 0x7fffu + ((u >> 16) & 1u);  // RNE
  return (ushort_t)(u >> 16);
}

__device__ __forceinline__ unsigned cvt_pk_bf16(float a, float b) {
  unsigned r;
  asm volatile("v_cvt_pk_bf16_f32 %0, %1, %2" : "=v"(r) : "v"(a), "v"(b));
  return r;  // lo16 = bf16(a), hi16 = bf16(b)
}

// async global->LDS, 16B per lane; LDS dest = wave-uniform base + lane*16
__device__ __forceinline__ void gload16(const void* g, void* l) {
  __builtin_amdgcn_global_load_lds(
      (const __attribute__((address_space(1))) unsigned int*)g,
      (__attribute__((address_space(3))) unsigned int*)l, 16, 0, 0);
}

// ---------------------------------------------------------------------------
// K0: fp32->bf16 conversion of x, qkv_w, proj_w PLUS zero-fill of invalid /
// pad rows in the K and V windowed planes (reference semantics: padded
// positions contribute zero K rows (score 0 -> exp(0)=1 in the denominator)
// and zero V rows). Q plane needs no fill: invalid query outputs are never
// stored, and poison bf16 (0xAAAA ~ -3e-13) is numerically benign.
// ---------------------------------------------------------------------------
__global__ __launch_bounds__(256) void conv_all(
    const float* __restrict__ x, const float* __restrict__ w1,
    const float* __restrict__ w2, ushort_t* __restrict__ xo,
    ushort_t* __restrict__ w1o, ushort_t* __restrict__ w2o,
    ushort_t* __restrict__ kpl, ushort_t* __restrict__ vpl) {
  constexpr int XN8 = (int)(XN / 8), WN8 = (int)(WN / 8), PN8 = (int)(PWN / 8);
  constexpr int TOT8 = XN8 + WN8 + PN8;
  constexpr int ZTOT = 50 * NTP * NH;  // 249,600 (bw,kk,head) triples
  const int i = blockIdx.x * 256 + threadIdx.x;
  if (i < TOT8) {
    const float* s;
    ushort_t* d;
    int j;
    if (i < XN8)            { s = x;  d = xo;  j = i; }
    else if (i < XN8 + WN8) { s = w1; d = w1o; j = i - XN8; }
    else                    { s = w2; d = w2o; j = i - XN8 - WN8; }
    const float4* s4 = (const float4*)s;
    float4 a = s4[2 * j], bq = s4[2 * j + 1];
    union { bf16x8 v; ushort_t u[8]; } o;
    o.u[0] = f2bf(a.x);  o.u[1] = f2bf(a.y);  o.u[2] = f2bf(a.z);  o.u[3] = f2bf(a.w);
    o.u[4] = f2bf(bq.x); o.u[5] = f2bf(bq.y); o.u[6] = f2bf(bq.z); o.u[7] = f2bf(bq.w);
    ((bf16x8*)d)[j] = o.v;
  } else if (i < TOT8 + ZTOT) {
    const int j = i - TOT8;
    const int pair = j / NH, head = j - pair * NH;
    const int bw = pair / NTP, kk = pair - bw * NTP;
    const int win = bw % NWIN, hi5 = win / 5, wi5 = win % 5;
    bool fill;
    if (kk >= NT) {
      fill = true;
    } else {
      const int rem = kk % 100;
      const int hh = rem / 10, ww2 = rem - hh * 10;
      fill = (hi5 == 4 && hh >= 4) || (wi5 == 4 && ww2 >= 4);
    }
    if (fill) {
      const size_t off = ((size_t)(bw * NH + head) * NTP + kk) * HD;
      bf16x8 z;
      z[0]=0;z[1]=0;z[2]=0;z[3]=0;z[4]=0;z[5]=0;z[6]=0;z[7]=0;
#pragma unroll
      for (int p = 0; p < 4; ++p) {
        ((bf16x8*)(kpl + off))[p] = z;
        ((bf16x8*)(vpl + off))[p] = z;
      }
    }
  }
}

// ---------------------------------------------------------------------------
// K1: dense QKV GEMM [15488 x 384] @ [384 x 1152]^T, m97 structure, BK=64:
// 6 staging phases, 32 MFMAs per compute phase. LDS 32KB (As/Bs 16KB, 128B
// row pitch = 8x16B chunks). Involution swizzle chunk^=(row&7) on gload
// source AND frag-read address (linear LDS dest). Linear grid 1089 with
// bijective XCD-chunk swizzle (q=136, r=1). Epilogue: direct uint2 scatter
// to window planes; Q pre-scaled by SCALE*LOG2E.
// ---------------------------------------------------------------------------
__global__ __launch_bounds__(256) void qkv_mfma(
    const ushort_t* __restrict__ xb, const ushort_t* __restrict__ wb,
    ushort_t* __restrict__ qpl, ushort_t* __restrict__ kpl,
    ushort_t* __restrict__ vpl) {
  __shared__ __align__(16) unsigned char As[16384];
  __shared__ __align__(16) unsigned char Bs[16384];
  // bijective XCD-chunk swizzle over 1089 work items (q=136, r=1)
  const unsigned bid = blockIdx.x;
  const unsigned xcd = bid & 7u, slot = bid >> 3;
  const unsigned wgid = (xcd == 0 ? 0u : 137u + (xcd - 1u) * 136u) + slot;
  const int nt = wgid % 9, mt = wgid / 9;
  const int tid = threadIdx.x, lane = tid & 63, wid = tid >> 6;
  const int wm = wid >> 1, wn = wid & 1;
  const int g = lane >> 4, q = lane & 15;
  const int m0 = mt * 128, n0 = nt * 128;

  const unsigned char* xB = (const unsigned char*)xb;
  const unsigned char* wB = (const unsigned char*)wb;

  size_t aoff[4], boff[4];
  unsigned ldsoff[4];
#pragma unroll
  for (int p = 0; p < 4; ++p) {
    const int row = wid * 32 + p * 8 + (lane >> 3);
    const int ch = lane & 7;                       // 16B chunk in 128B row
    const int gs = ch ^ (row & 7);                 // involution swizzle
    aoff[p] = (size_t)(m0 + row) * 768 + gs * 16;
    boff[p] = (size_t)(n0 + row) * 768 + gs * 16;
    ldsoff[p] = wid * 4096 + p * 1024;             // linear dest
  }

  f32x4 acc[4][4] = {};  // [i = N chunk][j = M chunk]

  for (int kb = 0; kb < 6; ++kb) {
    if (kb) __syncthreads();
#pragma unroll
    for (int p = 0; p < 4; ++p) {
      gload16(xB + aoff[p] + kb * 128, As + ldsoff[p]);
      gload16(wB + boff[p] + kb * 128, Bs + ldsoff[p]);
    }
    __syncthreads();
#pragma unroll
    for (int s = 0; s < 2; ++s) {
      bf16x8 tfr[4], wfr[4];
#pragma unroll
      for (int i = 0; i < 4; ++i) {
        const int ar = wm * 64 + i * 16 + q;  // token rows
        tfr[i] = *(const bf16x8*)(As + ar * 128 +
                                  (((s * 4 + g) ^ (ar & 7)) << 4));
        const int br = wn * 64 + i * 16 + q;  // weight rows
        wfr[i] = *(const bf16x8*)(Bs + br * 128 +
                                  (((s * 4 + g) ^ (br & 7)) << 4));
      }
#pragma unroll
      for (int i = 0; i < 4; ++i)
#pragma unroll
        for (int j = 0; j < 4; ++j)
          acc[i][j] = __builtin_amdgcn_mfma_f32_16x16x32_bf16(
              wfr[i], tfr[j], acc[i][j], 0, 0, 0);
    }
  }

  const float QS = SCALE * LOG2E;
#pragma unroll
  for (int j = 0; j < 4; ++j) {
    const int t = m0 + wm * 64 + j * 16 + q;  // token id (< 15488, guard-free)
    const int bt = t / NPOS, pos = t - bt * NPOS;
    const int h = pos / Ww, w = pos - h * Ww;
    const int b = bt >> 2, tt = bt & 3;
    const int hq = h / 10, wq = w / 10;
    const int kk = tt * 100 + (h - hq * 10) * 10 + (w - wq * 10);
    const int bw = b * NWIN + hq * 5 + wq;
#pragma unroll
    for (int i = 0; i < 4; ++i) {
      const int col = n0 + wn * 64 + i * 16 + 4 * g;
      const int which = col / Cc;
      const int head = (col - which * Cc) >> 5;
      const int d4 = col & 31;
      ushort_t* pl = which == 0 ? qpl : (which == 1 ? kpl : vpl);
      const float scl = which == 0 ? QS : 1.0f;
      uint2 st;
      st.x = cvt_pk_bf16(acc[i][j][0] * scl, acc[i][j][1] * scl);
      st.y = cvt_pk_bf16(acc[i][j][2] * scl, acc[i][j][3] * scl);
      *(uint2*)(pl + ((size_t)(bw * NH + head) * NTP + kk) * HD + d4) = st;
    }
  }
}

// ---------------------------------------------------------------------------
// K2: attention on contiguous per-(bw,head) planes. 600 blocks x 448 thr
// (7 waves): 4 blocks/CU -> all 600 blocks in ONE co-resident round (no
// inter-CU tail). Each wave walks query tiles {wid, wid+7}; V^T staged once
// in swizzled LDS, shared by both passes; K L1-resident on the second pass.
// Swapped QK^T, no-max in-register softmax, cvt_pk+permlane P relayout,
// setprio (T5).
// ---------------------------------------------------------------------------
__global__ __launch_bounds__(448) void attn_mfma(
    const ushort_t* __restrict__ qpl, const ushort_t* __restrict__ kpl,
    const ushort_t* __restrict__ vpl, ushort_t* __restrict__ aout) {
  __shared__ __align__(16) unsigned char Vt[32 * 896];

  const int wh = blockIdx.x;                   // plane index = bw*12+head
  const int head = wh % NH, bw = wh / NH;
  const int b = bw / NWIN, win = bw % NWIN, hi5 = win / 5, wi5 = win % 5;

  const int tid = threadIdx.x, lane = tid & 63, wid = tid >> 6;
  const int l31 = lane & 31, hi = lane >> 5;

  const ushort_t* qbase = qpl + (size_t)wh * (NTP * HD);
  const ushort_t* kbase = kpl + (size_t)wh * (NTP * HD);
  const ushort_t* vbase = vpl + (size_t)wh * (NTP * HD);

  // ---- stage V^T (contiguous reads; transposed swizzled writes) ----
  for (int slot = tid; slot < 1664; slot += 448) {
    const int key = slot >> 2, dblk = (slot & 3) * 8;
    union { bf16x8 v; ushort_t u[8]; } t;
    t.v = *(const bf16x8*)(vbase + (size_t)key * HD + dblk);
    const int kc = key >> 3, klo = key & 7;
#pragma unroll
    for (int j = 0; j < 8; ++j) {
      const int d = dblk + j;
      const int f = (d & 7) ^ ((d >> 3) & 3);
      *(ushort_t*)(Vt + d * 896 + ((kc ^ f) << 4) + klo * 2) = t.u[j];
    }
  }
  __syncthreads();

  const int fv = (l31 & 7) ^ ((l31 >> 3) & 3);  // V^T read swizzle for d=l31
  const unsigned char* vrow = Vt + l31 * 896;

  for (int tile = wid; tile < 13; tile += 7) {
    const int qrow = tile * 32 + l31;            // 0..415
    const ushort_t* qp = qbase + (size_t)qrow * HD;
    const bf16x8 qfa = *(const bf16x8*)(qp + hi * 8);
    const bf16x8 qfb = *(const bf16x8*)(qp + 16 + hi * 8);

    unsigned koff = (unsigned)l31 * HD;
    bf16x8 kf0 = *(const bf16x8*)(kbase + koff + hi * 8);
    bf16x8 kf1 = *(const bf16x8*)(kbase + koff + 16 + hi * 8);

    f32x16 o = {};
    float lpart = 0.f;

    for (int c = 0; c < 13; ++c) {
      f32x16 s = {};
      __builtin_amdgcn_s_setprio(1);
      s = __builtin_amdgcn_mfma_f32_32x32x16_bf16(kf0, qfa, s, 0, 0, 0);
      s = __builtin_amdgcn_mfma_f32_32x32x16_bf16(kf1, qfb, s, 0, 0, 0);
      __builtin_amdgcn_s_setprio(0);

      if (c < 12) {  // prefetch next chunk (planes padded to 416 rows)
        koff += 32u * HD;
        kf0 = *(const bf16x8*)(kbase + koff + hi * 8);
        kf1 = *(const bf16x8*)(kbase + koff + 16 + hi * 8);
      }

      if (c == 12) {  // keys 400..415 = tile rows 16..31 = regs 8..15 -> p=0
#pragma unroll
        for (int r = 8; r < 16; ++r) s[r] = -1e30f;
      }

      // ---- p = exp2(s) (no max subtraction), partial denominator ----
      float e[16];
#pragma unroll
      for (int r = 0; r < 16; ++r) e[r] = __builtin_amdgcn_exp2f(s[r]);
      lpart += ((e[0] + e[1]) + (e[2] + e[3])) + ((e[4] + e[5]) + (e[6] + e[7])) +
               (((e[8] + e[9]) + (e[10] + e[11])) +
                ((e[12] + e[13]) + (e[14] + e[15])));

      // ---- P^T -> bf16 B-frags (cvt_pk + permlane32_swap) ----
      unsigned w0 = cvt_pk_bf16(e[0], e[1]),   w1 = cvt_pk_bf16(e[2], e[3]);
      unsigned w2 = cvt_pk_bf16(e[4], e[5]),   w3 = cvt_pk_bf16(e[6], e[7]);
      unsigned w4 = cvt_pk_bf16(e[8], e[9]),   w5 = cvt_pk_bf16(e[10], e[11]);
      unsigned w6 = cvt_pk_bf16(e[12], e[13]), w7 = cvt_pk_bf16(e[14], e[15]);
      asm volatile("v_permlane32_swap_b32 %0, %1" : "+v"(w0), "+v"(w2));
      asm volatile("v_permlane32_swap_b32 %0, %1" : "+v"(w1), "+v"(w3));
      asm volatile("v_permlane32_swap_b32 %0, %1" : "+v"(w4), "+v"(w6));
      asm volatile("v_permlane32_swap_b32 %0, %1" : "+v"(w5), "+v"(w7));
      union { bf16x8 v; unsigned u[4]; } p0, p1;
      p0.u[0] = w0; p0.u[1] = w1; p0.u[2] = w2; p0.u[3] = w3;
      p1.u[0] = w4; p1.u[1] = w5; p1.u[2] = w6; p1.u[3] = w7;

      // ---- PV: O^T += V^T @ P^T ----
      const bf16x8 vf0 = *(const bf16x8*)(vrow + (((4 * c + hi) ^ fv) << 4));
      const bf16x8 vf1 = *(const bf16x8*)(vrow + (((4 * c + 2 + hi) ^ fv) << 4));
      __builtin_amdgcn_s_setprio(1);
      o = __builtin_amdgcn_mfma_f32_32x32x16_bf16(vf0, p0.v, o, 0, 0, 0);
      o = __builtin_amdgcn_mfma_f32_32x32x16_bf16(vf1, p1.v, o, 0, 0, 0);
      __builtin_amdgcn_s_setprio(0);
    }

    lpart += __shfl_xor(lpart, 32);

    // ---- epilogue: normalize, store bf16 to [token][384] ----
    {
      const int tt = qrow / 100, rem = qrow - tt * 100;
      const int hh = rem / 10, ww2 = rem - hh * 10;
      const int h = hi5 * 10 + hh, w = wi5 * 10 + ww2;
      if (qrow < NT && h < Hh && w < Ww) {
        const int qtok = (b * Tt + tt) * NPOS + h * Ww + w;
        ushort_t* dst = aout + (size_t)qtok * Cc + head * HD;
        const float inv = 1.0f / lpart;
#pragma unroll
        for (int g4 = 0; g4 < 4; ++g4) {
          unsigned lo  = cvt_pk_bf16(o[4 * g4 + 0] * inv, o[4 * g4 + 1] * inv);
          unsigned hi2 = cvt_pk_bf16(o[4 * g4 + 2] * inv, o[4 * g4 + 3] * inv);
          uint2 st; st.x = lo; st.y = hi2;
          *(uint2*)(dst + 8 * g4 + 4 * hi) = st;
        }
      }
    }
  }
}

// ---------------------------------------------------------------------------
// K3: projection GEMM [15488 x 384] @ [384 x 384]^T + bias -> fp32 out.
// BK=64 (same proven transform as K1): 6 staging phases, 32 MFMAs per
// compute phase, involution swizzle chunk^=(row&7). Swapped operands:
// D-rows = 4 consecutive N-cols -> float4 stores.
// ---------------------------------------------------------------------------
__global__ __launch_bounds__(256) void proj_mfma(
    const ushort_t* __restrict__ ab, const ushort_t* __restrict__ pw,
    const float* __restrict__ bias, float* __restrict__ out) {
  __shared__ __align__(16) unsigned char As[16384];
  __shared__ __align__(16) unsigned char Bs[16384];
  const int nt = blockIdx.x, mt = blockIdx.y;
  const int tid = threadIdx.x, lane = tid & 63, wid = tid >> 6;
  const int wm = wid >> 1, wn = wid & 1;
  const int g = lane >> 4, q = lane & 15;
  const int m0 = mt * 128, n0 = nt * 128;

  const unsigned char* aB = (const unsigned char*)ab;
  const unsigned char* wB = (const unsigned char*)pw;

  size_t aoff[4], boff[4];
  unsigned ldsoff[4];
#pragma unroll
  for (int p = 0; p < 4; ++p) {
    const int row = wid * 32 + p * 8 + (lane >> 3);
    const int ch = lane & 7;
    const int gs = ch ^ (row & 7);
    aoff[p] = (size_t)(m0 + row) * 768 + gs * 16;
    boff[p] = (size_t)(n0 + row) * 768 + gs * 16;
    ldsoff[p] = wid * 4096 + p * 1024;
  }

  f32x4 acc[4][4] = {};  // [i = N chunk][j = M chunk]

  for (int kb = 0; kb < 6; ++kb) {
    if (kb) __syncthreads();
#pragma unroll
    for (int p = 0; p < 4; ++p) {
      gload16(aB + aoff[p] + kb * 128, As + ldsoff[p]);
      gload16(wB + boff[p] + kb * 128, Bs + ldsoff[p]);
    }
    __syncthreads();
#pragma unroll
    for (int s = 0; s < 2; ++s) {
      bf16x8 tfr[4], wfr[4];
#pragma unroll
      for (int i = 0; i < 4; ++i) {
        const int ar = wm * 64 + i * 16 + q;
        tfr[i] = *(const bf16x8*)(As + ar * 128 +
                                  (((s * 4 + g) ^ (ar & 7)) << 4));
        const int br = wn * 64 + i * 16 + q;
        wfr[i] = *(const bf16x8*)(Bs + br * 128 +
                                  (((s * 4 + g) ^ (br & 7)) << 4));
      }
#pragma unroll
      for (int i = 0; i < 4; ++i)
#pragma unroll
        for (int j = 0; j < 4; ++j)
          acc[i][j] = __builtin_amdgcn_mfma_f32_16x16x32_bf16(
              wfr[i], tfr[j], acc[i][j], 0, 0, 0);
    }
  }

#pragma unroll
  for (int j = 0; j < 4; ++j) {
    const int t = m0 + wm * 64 + j * 16 + q;
#pragma unroll
    for (int i = 0; i < 4; ++i) {
      const int col = n0 + wn * 64 + i * 16 + 4 * g;
      const float4 bb = *(const float4*)(bias + col);
      float4 st;
      st.x = acc[i][j][0] + bb.x;
      st.y = acc[i][j][1] + bb.y;
      st.z = acc[i][j][2] + bb.z;
      st.w = acc[i][j][3] + bb.w;
      *(float4*)(out + (size_t)t * Cc + col) = st;
    }
  }
}

// ---------------------------------------------------------------------------
extern "C" void kernel_launch(void* const* d_in, const int* in_sizes, int n_in,
                              void* d_out, int out_size, void* d_ws,
                              size_t ws_size, hipStream_t stream) {
  const float* x      = (const float*)d_in[0];
  const float* qkv_w  = (const float*)d_in[1];
  const float* proj_w = (const float*)d_in[2];
  const float* proj_b = (const float*)d_in[3];

  ushort_t* xb    = (ushort_t*)d_ws;      // [15488][384] bf16
  ushort_t* wb    = xb + XN;              // [1152][384] bf16
  ushort_t* pwb   = wb + WN;              // [384][384] bf16
  ushort_t* qpl   = pwb + PWN;            // [600][416][32] bf16 planes
  ushort_t* kpl   = qpl + PLN;
  ushort_t* vpl   = kpl + PLN;
  ushort_t* attnb = vpl + PLN;            // [15488][384] bf16
  // total ~73 MB of d_ws

  constexpr int TOT8 = (int)((XN + WN + PWN) / 8);
  constexpr int ZTOT = 50 * NTP * NH;
  conv_all<<<(TOT8 + ZTOT + 255) / 256, 256, 0, stream>>>(
      x, qkv_w, proj_w, xb, wb, pwb, kpl, vpl);
  qkv_mfma<<<1089, 256, 0, stream>>>(xb, wb, qpl, kpl, vpl);
  attn_mfma<<<600, 448, 0, stream>>>(qpl, kpl, vpl, attnb);
  proj_mfma<<<dim3(3, 121), 256, 0, stream>>>(attnb, pwb, proj_b, (float*)d_out);
}